// Round 16
// baseline (29.588 us; speedup 1.0000x reference)
//
#include <hip/hip_runtime.h>
#include <math.h>

#define NSEG 2048
#define ROW 65
#define N2D (65 * ROW)     // 2D knot table size (4225)

// ---- K1: pre_ab only (65 blocks x 256) -> bpg, knots2d, coef2d ----
__global__ __launch_bounds__(256) void k_pre_ab(
    const float* __restrict__ W1, const float* __restrict__ b1,
    const float* __restrict__ W2, const float* __restrict__ b2,
    const float* __restrict__ W3,
    float* __restrict__ bpg, float* __restrict__ knots, float2* __restrict__ coef)
{
    __shared__ float bps[64];
    __shared__ float w2s[64 * 65];   // padded: row stride 65 kills bank conflicts
    __shared__ float sc_[64], sda[64], sdb[64];
    const int tid = threadIdx.x;
    const int k = blockIdx.x;
    const int lane = tid & 63;

    if (tid < 64) {
        // breakpoints: t = -b1/W1 (W1==0 -> sentinel), stable shfl rank-sort
        float w1l = W1[lane], b1l = b1[lane];
        float t = (w1l != 0.0f) ? (-b1l / w1l) : 3.0e38f;
        int r = 0;
        for (int l = 0; l < 64; ++l) {
            float o = __shfl(t, l);
            r += (o < t) || (o == t && l < lane);
        }
        bps[r] = t;
    }
    for (int i = tid; i < 4096; i += 256)
        w2s[(i >> 6) * 65 + (i & 63)] = W2[i];
    __syncthreads();
    if (k == 0 && tid < 64) bpg[lane] = bps[lane];

    float a0 = 0.0f, b0 = 0.0f;
    if (tid < 64) {
        // affine coeffs of z_i (i = lane) on interval k: z = a*x + b
        float lof = (k == 0) ? (bps[0] - 1.0f) : bps[k - 1];
        float hif = (k == 64) ? (bps[63] + 1.0f) : bps[k];
        float xm = lof + 0.5f * (hif - lof);
        float a = 0.0f, b = b2[lane];
        for (int j = 0; j < 64; ++j) {
            float w1 = W1[j];
            if (w1 * xm + b1[j] > 0.0f) {
                float w2 = w2s[lane * 65 + j];
                a += w2 * w1;
                b += w2 * b1[j];
            }
        }

        float w3 = W3[lane];
        float lo = (k == 0) ? -INFINITY : bps[k - 1];
        float hi = (k == 64) ? INFINITY : bps[k];
        float c = INFINITY, da = 0.0f, db = 0.0f;
        if (a != 0.0f) {
            float cc = -b / a;
            if (cc > lo && cc < hi) {
                float s = (a > 0.0f) ? 1.0f : -1.0f;
                c = cc; da = s * w3 * a; db = s * w3 * b;
            }
        }
        bool act;
        if (k == 0) act = (a < 0.0f) || (a == 0.0f && b > 0.0f);
        else { float v = a * lo + b; act = (v > 0.0f) || (v == 0.0f && a > 0.0f); }
        a0 = act ? w3 * a : 0.0f;
        b0 = act ? w3 * b : 0.0f;
        for (int d = 32; d; d >>= 1) { a0 += __shfl_xor(a0, d); b0 += __shfl_xor(b0, d); }

        int rank = 0;
        for (int l = 0; l < 64; ++l) {
            float o = __shfl(c, l);
            rank += (o < c) || (o == c && l < lane);
        }
        sc_[rank] = c; sda[rank] = da; sdb[rank] = db;
    }
    __syncthreads();
    if (tid < 64) {
        float cs = sc_[lane], das = sda[lane], dbs = sdb[lane];
        for (int d = 1; d < 64; d <<= 1) {  // inclusive scan in sorted order
            float ta = __shfl_up(das, d);
            float tb = __shfl_up(dbs, d);
            if (lane >= d) { das += ta; dbs += tb; }
        }
        knots[k * ROW + lane] = cs;          // inf for invalid -> fine-search safe
        if (lane == 0) coef[k * ROW] = make_float2(a0, b0);
        coef[k * ROW + lane + 1] = make_float2(a0 + das, b0 + dbs);
    }
}

// wave-parallel lower_bound: first i with batch[i] >= target (64-ary search).
__device__ __forceinline__ int wave_lower_bound(const int* __restrict__ batch,
                                                int n, int target, int lane)
{
    long long lo = -1, hi = n;
    while (hi - lo > 65) {
        long long d = hi - lo;
        long long q = lo + 1 + (((d - 1) * lane) >> 6);   // 64 monotone probes in (lo, hi)
        int v = batch[q];
        unsigned long long m = __ballot(v < target);      // monotone -> prefix mask
        int c = (int)__popcll(m);
        long long nlo = (c > 0) ? (lo + 1 + (((d - 1) * (c - 1)) >> 6)) : lo;
        long long nhi = (c < 64) ? (lo + 1 + (((d - 1) * c) >> 6)) : hi;
        lo = nlo; hi = nhi;
    }
    long long q = lo + 1 + lane;
    int v = (q < hi) ? batch[q] : 0x7fffffff;
    unsigned long long m = __ballot(v < target);
    return (int)(lo + 1 + __popcll(m));
}

// 8-ary count of entries <= x over a 64-entry sorted array at base p.
// Round 1: 8 stride-8 probes (fixed indices); round 2: 7 probes in the octant.
// Returns #{p[0..63] <= x} in [0,64]. 2 dependent LDS rounds instead of 6.
__device__ __forceinline__ int count_le_64(const float* __restrict__ p, float xv)
{
    int c1 = 0;
#pragma unroll
    for (int i = 0; i < 8; ++i) c1 += (p[8 * i + 7] <= xv);
    int b = (c1 < 8) ? (c1 << 3) : 56;
    int c2 = 0;
#pragma unroll
    for (int d = 0; d < 7; ++d) c2 += (p[b + d] <= xv);
    return b + c2 + (c1 >> 3);     // c1==8 -> all 64 entries <= x
}

// ---- K2: one block per segment -> self-located bounds, 8-ary two-level eval,
//          deterministic f64 reduce, broadcast write ----
__global__ __launch_bounds__(256) void k_eval_out(
    const float* __restrict__ x, const int* __restrict__ batch,
    const float* __restrict__ bpg, const float* __restrict__ knots2d,
    const float2* __restrict__ coef2d,
    const float* __restrict__ b3, float* __restrict__ out, int n)
{
    __shared__ float bps_s[64];
    __shared__ __align__(16) float T2_s[N2D];
    __shared__ int bounds_s[2];
    __shared__ double wsum[4];
    __shared__ float w_s;
    const int tid = threadIdx.x;
    const int wv = tid >> 6;
    const int lane = tid & 63;
    const int s = blockIdx.x;

    // waves 0,1: locate this segment's [start, end) via 64-ary search over batch;
    // waves 2,3: stage breakpoints + 2D knot table (17 KB, float4) meanwhile.
    if (wv == 0) {
        int st = wave_lower_bound(batch, n, s, lane);
        if (lane == 0) bounds_s[0] = st;
    } else if (wv == 1) {
        int en = wave_lower_bound(batch, n, s + 1, lane);
        if (lane == 0) bounds_s[1] = en;
    } else {
        if (wv == 2) bps_s[lane] = bpg[lane];
        const int tid2 = tid - 128;
        for (int i = tid2; i < (N2D >> 2); i += 128)
            ((float4*)T2_s)[i] = ((const float4*)knots2d)[i];
        if (tid2 == 0) T2_s[N2D - 1] = knots2d[N2D - 1];
    }
    __syncthreads();
    const int start = bounds_s[0];
    const int end   = bounds_s[1];
    if (start >= end) return;          // empty segment: nothing to write

    // eval + per-thread f64 accumulate over the segment's contiguous run
    double acc = 0.0;
    for (int i = start + tid; i < end; i += 256) {
        float xv = x[i];
        int k = count_le_64(bps_s, xv);        // coarse (round1 = broadcast probes)
        int j = count_le_64(T2_s + k * ROW, xv); // fine
        float2 ab = coef2d[k * ROW + j];       // 33.8 KB table, L1/L2 resident
        acc += (double)fmaf(ab.x, xv, ab.y);
    }

    // deterministic tree reduction: wave shfl + 4 partials in LDS
    for (int d = 32; d; d >>= 1) acc += __shfl_down(acc, d);
    if ((tid & 63) == 0) wsum[tid >> 6] = acc;
    __syncthreads();
    if (tid == 0) {
        double tot = wsum[0] + wsum[1] + wsum[2] + wsum[3];
        double mean = tot / (double)(end - start);
        w_s = fmaxf((float)(mean + (double)b3[0]), 0.0f);
    }
    __syncthreads();
    const float w = w_s;
    for (int i = start + tid; i < end; i += 256) out[i] = w;
}

extern "C" void kernel_launch(void* const* d_in, const int* in_sizes, int n_in,
                              void* d_out, int out_size, void* d_ws, size_t ws_size,
                              hipStream_t stream)
{
    const float* x   = (const float*)d_in[0];
    const int* batch = (const int*)d_in[1];
    const float* W1 = (const float*)d_in[2];
    const float* b1 = (const float*)d_in[3];
    const float* W2 = (const float*)d_in[4];
    const float* b2 = (const float*)d_in[5];
    const float* W3 = (const float*)d_in[6];
    const float* b3 = (const float*)d_in[7];
    float* out = (float*)d_out;
    const int n = in_sizes[0];

    char* ws = (char*)d_ws;
    float*  bpg      = (float*)ws;                          //   256  -> 256
    float*  knots2d  = (float*)(ws + 256);                  // 16912  -> 17168
    float2* coef2d   = (float2*)(ws + 17168);               // 33808  -> 50976

    k_pre_ab<<<65, 256, 0, stream>>>(W1, b1, W2, b2, W3, bpg, knots2d, coef2d);
    k_eval_out<<<NSEG, 256, 0, stream>>>(x, batch, bpg, knots2d, coef2d,
                                         b3, out, n);
}

// Round 17
// 28.797 us; speedup vs baseline: 1.0275x; 1.0275x over previous
//
#include <hip/hip_runtime.h>
#include <math.h>

#define NSEG 2048
#define MMAX 4226          // max flat coef entries (M+1), M <= 64*65+64 = 4224
#define TCAP 4240          // flat knot array capacity incl window-read padding
#define NC 4096            // grid cells
#define GLO (-9.0f)
#define GHI (9.0f)
#define DXF ((GHI - GLO) / NC)
#define INVDX (NC / (GHI - GLO))
#define SCAN_PPT 8         // points per scan thread in K1
#define MAGIC 0x5EC7A100u  // low 7 bits clear: tag | nvalid

// ---- K1: blocks 0..64: pre_ab + in-launch flatten (publish/spin on nvalid);
//          blocks 65..: segment-boundary scan over sorted batch ----
__global__ __launch_bounds__(256) void k_pre(
    const float* __restrict__ W1, const float* __restrict__ b1,
    const float* __restrict__ W2, const float* __restrict__ b2,
    const float* __restrict__ W3, const int* __restrict__ batch,
    unsigned int* __restrict__ nv_pub, int* __restrict__ Mg,
    float* __restrict__ Tf, float2* __restrict__ Cf,
    unsigned short* __restrict__ baseg,
    int* __restrict__ seg_start, int* __restrict__ seg_end, int n)
{
    __shared__ float bps[64];
    __shared__ float w2s[64 * 65];   // padded: row stride 65 kills bank conflicts
    __shared__ float cr_[64], sda[64], sdb[64];
    __shared__ float ca_[65], cb_[65];
    __shared__ int nvLDS[65];
    __shared__ int off_s, M_s;
    const int tid = threadIdx.x;

    if (blockIdx.x >= 65) {
        // ---- segment scan: dense seg_start/seg_end over sorted batch ----
        int bid2 = blockIdx.x - 65;
        int base = bid2 * (256 * SCAN_PPT) + tid * SCAN_PPT;
        if (base >= n) return;
        const int4* bp = (const int4*)(batch + base);
        int4 a4 = bp[0], b4 = bp[1];
        int ss[SCAN_PPT] = {a4.x, a4.y, a4.z, a4.w, b4.x, b4.y, b4.z, b4.w};
        int prev = (base > 0) ? batch[base - 1] : -1;
#pragma unroll
        for (int p = 0; p < SCAN_PPT; ++p) {
            int u = (p == 0) ? prev : ss[p - 1];
            int v = ss[p];
            if (v != u) {
                int i = base + p;
                for (int s = (u > 0 ? u : 0); s < v; ++s) seg_end[s] = i;
                for (int s = u + 1; s <= v; ++s) seg_start[s] = i;
            }
        }
        if (base + SCAN_PPT >= n) {   // true last thread (n % SCAN_PPT == 0)
            int u = ss[SCAN_PPT - 1];
            for (int s = u; s < NSEG; ++s) seg_end[s] = n;
            for (int s = u + 1; s < NSEG; ++s) seg_start[s] = n;
        }
        return;
    }

    // ---- pre_ab: per-interval crossing tables (wave 0 does the wave math) ----
    const int k = blockIdx.x;
    const int lane = tid & 63;

    if (tid < 64) {
        // breakpoints: t = -b1/W1 (W1==0 -> sentinel), stable shfl rank-sort
        float w1l = W1[lane], b1l = b1[lane];
        float t = (w1l != 0.0f) ? (-b1l / w1l) : 3.0e38f;
        int r = 0;
        for (int l = 0; l < 64; ++l) {
            float o = __shfl(t, l);
            r += (o < t) || (o == t && l < lane);
        }
        bps[r] = t;
    }
    for (int i = tid; i < 4096; i += 256)
        w2s[(i >> 6) * 65 + (i & 63)] = W2[i];
    __syncthreads();

    float a0 = 0.0f, b0 = 0.0f;
    if (tid < 64) {
        // affine coeffs of z_i (i = lane) on interval k: z = a*x + b
        float lof = (k == 0) ? (bps[0] - 1.0f) : bps[k - 1];
        float hif = (k == 64) ? (bps[63] + 1.0f) : bps[k];
        float xm = lof + 0.5f * (hif - lof);
        float a = 0.0f, b = b2[lane];
        for (int j = 0; j < 64; ++j) {
            float w1 = W1[j];
            if (w1 * xm + b1[j] > 0.0f) {
                float w2 = w2s[lane * 65 + j];
                a += w2 * w1;
                b += w2 * b1[j];
            }
        }

        float w3 = W3[lane];
        float lo = (k == 0) ? -INFINITY : bps[k - 1];
        float hi = (k == 64) ? INFINITY : bps[k];
        float c = INFINITY, da = 0.0f, db = 0.0f;
        if (a != 0.0f) {
            float cc = -b / a;
            if (cc > lo && cc < hi) {
                float s = (a > 0.0f) ? 1.0f : -1.0f;
                c = cc; da = s * w3 * a; db = s * w3 * b;
            }
        }
        bool act;
        if (k == 0) act = (a < 0.0f) || (a == 0.0f && b > 0.0f);
        else { float v = a * lo + b; act = (v > 0.0f) || (v == 0.0f && a > 0.0f); }
        a0 = act ? w3 * a : 0.0f;
        b0 = act ? w3 * b : 0.0f;
        for (int d = 32; d; d >>= 1) { a0 += __shfl_xor(a0, d); b0 += __shfl_xor(b0, d); }

        // publish nvalid EARLY (count of finite crossings), magic-tagged
        unsigned long long vm = __ballot(isfinite(c));
        int nv = (int)__popcll(vm);
        if (lane == 0)
            __hip_atomic_store(&nv_pub[k], MAGIC | (unsigned)nv,
                               __ATOMIC_RELEASE, __HIP_MEMORY_SCOPE_AGENT);

        // stable rank sort of crossings (inf = invalid go last); scatter via LDS
        int rank = 0;
        for (int l = 0; l < 64; ++l) {
            float o = __shfl(c, l);
            rank += (o < c) || (o == c && l < lane);
        }
        cr_[rank] = c; sda[rank] = da; sdb[rank] = db;
    }
    __syncthreads();
    if (tid < 64) {
        float das = sda[lane], dbs = sdb[lane];
        for (int d = 1; d < 64; d <<= 1) {  // inclusive scan in sorted order
            float ta = __shfl_up(das, d);
            float tb = __shfl_up(dbs, d);
            if (lane >= d) { das += ta; dbs += tb; }
        }
        if (lane == 0) { ca_[0] = a0; cb_[0] = b0; }
        ca_[lane + 1] = a0 + das;           // cumulative coef after crossing 'lane'
        cb_[lane + 1] = b0 + dbs;
    }

    // ---- spin for all 65 published nvalid (all 65 blocks co-resident) ----
    if (tid < 65) {
        unsigned v;
        for (;;) {
            v = __hip_atomic_load(&nv_pub[tid], __ATOMIC_ACQUIRE,
                                  __HIP_MEMORY_SCOPE_AGENT);
            if ((v & 0xFFFFFF80u) == MAGIC) break;
            __builtin_amdgcn_s_sleep(1);
        }
        nvLDS[tid] = (int)(v & 0x7Fu);
    }
    __syncthreads();
    if (tid < 64) {  // off[k] = sum_{k'<k}(nv+1) via wave scan; M for sentinels
        int v = nvLDS[lane] + 1;
        int sc = v;
        for (int d = 1; d < 64; d <<= 1) {
            int tt = __shfl_up(sc, d);
            if (lane >= d) sc += tt;
        }
        int offk  = (k == 0) ? 0 : __shfl(sc, k - 1);
        int off64 = __shfl(sc, 63);
        if (lane == 0) { off_s = offk; M_s = off64 + nvLDS[64]; }
    }
    __syncthreads();
    const int offk = off_s;
    const int M    = M_s;
    const int nv   = nvLDS[k];

    // ---- flat row slice: nv fine knots, then coarse bps[k] (k<64) ----
    for (int j = tid; j <= nv; j += 256) {
        if (j < nv) Tf[offk + j] = cr_[j];
        else if (k < 64) Tf[offk + j] = bps[k];
        Cf[offk + j] = make_float2(ca_[j], cb_[j]);
    }
    if (k == 64) {  // sentinels + coef pad beyond M; publish M
        float2 lastC = make_float2(ca_[nv], cb_[nv]);
        for (int i = M + tid; i < TCAP; i += 256) Tf[i] = INFINITY;
        for (int i = M + 1 + tid; i < MMAX; i += 256) Cf[i] = lastC;
        if (tid == 0) Mg[0] = M;
    }

    // ---- grid cells owned by interval k: left in [bps[k-1], bps[k]) ----
    float lob = (k == 0) ? GLO : bps[k - 1];
    float hib = (k == 64) ? GHI : bps[k];
    float clo = fminf(fmaxf((lob - GLO) * INVDX, 0.0f), (float)(NC - 1));
    float chi = fminf(fmaxf((hib - GLO) * INVDX, 0.0f), (float)(NC - 1));
    int c0 = max(0, (int)clo - 1);
    int c1 = min(NC - 1, (int)chi + 1);
    for (int c = c0 + tid; c <= c1; c += 256) {
        float left = GLO + c * DXF;
        bool ok = (k == 0 || left >= bps[k - 1]) && (k == 64 || left < bps[k]);
        if (ok) {
            int j = 0;  // #{fine knots <= left}; inf-padding makes 64-search safe
#pragma unroll
            for (int ofs = 32; ofs >= 1; ofs >>= 1)
                if (cr_[j + ofs - 1] <= left) j += ofs;
            if (j < 64 && cr_[j] <= left) ++j;
            baseg[c] = (unsigned short)(offk + j);
        }
    }
}

// ---- K2: one block per segment -> LDS window eval, f64 reduce, broadcast ----
// Per point: 1 LDS ushort (base) + 3 LDS b128 (window) + 1 global L1 (Cf).
__global__ __launch_bounds__(256) void k_eval_out(
    const float* __restrict__ x,
    const int* __restrict__ seg_start, const int* __restrict__ seg_end,
    const float* __restrict__ Tf, const float2* __restrict__ Cf,
    const unsigned short* __restrict__ baseg, const int* __restrict__ Mg,
    const float* __restrict__ b3, float* __restrict__ out)
{
    __shared__ __align__(16) float T_s[TCAP];        // 16960 B
    __shared__ unsigned short base_s[NC];            //  8192 B
    __shared__ double wsum[4];
    __shared__ float w_s;
    const int tid = threadIdx.x;
    const int s = blockIdx.x;

    // stage live knot table + grid (L2 broadcast)
    const int stageN = min(TCAP, (Mg[0] + 32) & ~15);
    for (int i = tid; i < (stageN >> 2); i += 256)
        ((float4*)T_s)[i] = ((const float4*)Tf)[i];
    for (int i = tid; i < NC / 2; i += 256)
        ((unsigned int*)base_s)[i] = ((const unsigned int*)baseg)[i];

    const int start = seg_start[s];
    const int end   = seg_end[s];
    __syncthreads();
    if (start >= end) return;          // empty segment: nothing to write

    // eval + per-thread f64 accumulate over the segment's contiguous run
    double acc = 0.0;
    for (int i = start + tid; i < end; i += 256) {
        float xv = x[i];
        int m;
        if (xv >= GLO) {
            int c = (int)((xv - GLO) * INVDX);
            c = c < NC - 1 ? c : NC - 1;
            if (c > 0 && GLO + c * DXF > xv) --c;  // fp rounding guard
            int b0i = base_s[c];
            int a0 = b0i & ~3;
            // 12-entry LDS window from a0: entries below b0i are <= x by grid
            // construction, so m = a0 + count(T[a0..a0+11] <= x).
            const float4* tw = (const float4*)(T_s + a0);
            float4 t0 = tw[0], t1 = tw[1], t2 = tw[2];
            int cw = (t0.x <= xv) + (t0.y <= xv) + (t0.z <= xv) + (t0.w <= xv)
                   + (t1.x <= xv) + (t1.y <= xv) + (t1.z <= xv) + (t1.w <= xv)
                   + (t2.x <= xv) + (t2.y <= xv) + (t2.z <= xv) + (t2.w <= xv);
            m = a0 + cw;
            if (cw == 12) { while (T_s[m] <= xv) ++m; }  // ~never taken
        } else m = 0;
        float2 ab = Cf[m];                         // global L1 (34 KB, hot)
        acc += (double)fmaf(ab.x, xv, ab.y);
    }

    // deterministic tree reduction: wave shfl + 4 partials in LDS
    for (int d = 32; d; d >>= 1) acc += __shfl_down(acc, d);
    if ((tid & 63) == 0) wsum[tid >> 6] = acc;
    __syncthreads();
    if (tid == 0) {
        double tot = wsum[0] + wsum[1] + wsum[2] + wsum[3];
        double mean = tot / (double)(end - start);
        w_s = fmaxf((float)(mean + (double)b3[0]), 0.0f);
    }
    __syncthreads();
    const float w = w_s;
    for (int i = start + tid; i < end; i += 256) out[i] = w;
}

extern "C" void kernel_launch(void* const* d_in, const int* in_sizes, int n_in,
                              void* d_out, int out_size, void* d_ws, size_t ws_size,
                              hipStream_t stream)
{
    const float* x   = (const float*)d_in[0];
    const int* batch = (const int*)d_in[1];
    const float* W1 = (const float*)d_in[2];
    const float* b1 = (const float*)d_in[3];
    const float* W2 = (const float*)d_in[4];
    const float* b2 = (const float*)d_in[5];
    const float* W3 = (const float*)d_in[6];
    const float* b3 = (const float*)d_in[7];
    float* out = (float*)d_out;
    const int n = in_sizes[0];

    char* ws = (char*)d_ws;
    int*    seg_start = (int*)ws;                           //  8192  -> 8192
    int*    seg_end   = (int*)(ws + 8192);                  //  8192  -> 16384
    unsigned int* nv_pub = (unsigned int*)(ws + 16384);     //   272  -> 16656
    int*    Mg        = (int*)(ws + 16656);                 //    16  -> 16672
    float*  Tflat     = (float*)(ws + 16672);               // 16960  -> 33632 (16B-aligned)
    float2* Cflat     = (float2*)(ws + 33632);              // 33808  -> 67440
    unsigned short* baseg = (unsigned short*)(ws + 67440);  //  8192  -> 75632

    const int scanBlocks = (n + 256 * SCAN_PPT - 1) / (256 * SCAN_PPT);
    k_pre<<<65 + scanBlocks, 256, 0, stream>>>(
        W1, b1, W2, b2, W3, batch, nv_pub, Mg, Tflat, Cflat, baseg,
        seg_start, seg_end, n);
    k_eval_out<<<NSEG, 256, 0, stream>>>(x, seg_start, seg_end, Tflat, Cflat,
                                         baseg, Mg, b3, out);
}

// Round 18
// 27.252 us; speedup vs baseline: 1.0857x; 1.0567x over previous
//
#include <hip/hip_runtime.h>
#include <math.h>

#define NSEG 2048
#define ROW 65
#define N2D (65 * ROW)     // 2D knot table size (4225)
#define SCAN_PPT 8         // points per scan thread in K1

// ---- K1: pre_ab (blocks 0..64) + segment-boundary scan (blocks 65..) ----
__global__ __launch_bounds__(256) void k_pre_scan(
    const float* __restrict__ W1, const float* __restrict__ b1,
    const float* __restrict__ W2, const float* __restrict__ b2,
    const float* __restrict__ W3, const int* __restrict__ batch,
    float* __restrict__ bpg, float* __restrict__ knots, float2* __restrict__ coef,
    int* __restrict__ seg_start, int* __restrict__ seg_end, int n)
{
    __shared__ float bps[64];
    __shared__ float w2s[64 * 65];   // padded: row stride 65 kills bank conflicts
    __shared__ float sc_[64], sda[64], sdb[64];
    const int tid = threadIdx.x;

    if (blockIdx.x >= 65) {
        // ---- segment scan: dense seg_start/seg_end over sorted batch ----
        int bid2 = blockIdx.x - 65;
        int base = bid2 * (256 * SCAN_PPT) + tid * SCAN_PPT;
        if (base >= n) return;
        const int4* bp = (const int4*)(batch + base);
        int4 a4 = bp[0], b4 = bp[1];
        int ss[SCAN_PPT] = {a4.x, a4.y, a4.z, a4.w, b4.x, b4.y, b4.z, b4.w};
        int prev = (base > 0) ? batch[base - 1] : -1;
#pragma unroll
        for (int p = 0; p < SCAN_PPT; ++p) {
            int u = (p == 0) ? prev : ss[p - 1];
            int v = ss[p];
            if (v != u) {
                int i = base + p;
                for (int s = (u > 0 ? u : 0); s < v; ++s) seg_end[s] = i;
                for (int s = u + 1; s <= v; ++s) seg_start[s] = i;
            }
        }
        if (base + SCAN_PPT >= n) {   // true last thread (n % SCAN_PPT == 0)
            int u = ss[SCAN_PPT - 1];
            for (int s = u; s < NSEG; ++s) seg_end[s] = n;
            for (int s = u + 1; s < NSEG; ++s) seg_start[s] = n;
        }
        return;
    }

    // ---- pre_ab: per-interval crossing tables (wave 0 does the wave math) ----
    const int k = blockIdx.x;
    const int lane = tid & 63;

    if (tid < 64) {
        // breakpoints: t = -b1/W1 (W1==0 -> sentinel), stable shfl rank-sort
        float w1l = W1[lane], b1l = b1[lane];
        float t = (w1l != 0.0f) ? (-b1l / w1l) : 3.0e38f;
        int r = 0;
        for (int l = 0; l < 64; ++l) {
            float o = __shfl(t, l);
            r += (o < t) || (o == t && l < lane);
        }
        bps[r] = t;
    }
    for (int i = tid; i < 4096; i += 256)
        w2s[(i >> 6) * 65 + (i & 63)] = W2[i];
    __syncthreads();
    if (k == 0 && tid < 64) bpg[lane] = bps[lane];

    float a0 = 0.0f, b0 = 0.0f;
    if (tid < 64) {
        // affine coeffs of z_i (i = lane) on interval k: z = a*x + b
        float lof = (k == 0) ? (bps[0] - 1.0f) : bps[k - 1];
        float hif = (k == 64) ? (bps[63] + 1.0f) : bps[k];
        float xm = lof + 0.5f * (hif - lof);
        float a = 0.0f, b = b2[lane];
        for (int j = 0; j < 64; ++j) {
            float w1 = W1[j];
            if (w1 * xm + b1[j] > 0.0f) {
                float w2 = w2s[lane * 65 + j];
                a += w2 * w1;
                b += w2 * b1[j];
            }
        }

        float w3 = W3[lane];
        float lo = (k == 0) ? -INFINITY : bps[k - 1];
        float hi = (k == 64) ? INFINITY : bps[k];
        float c = INFINITY, da = 0.0f, db = 0.0f;
        if (a != 0.0f) {
            float cc = -b / a;
            if (cc > lo && cc < hi) {
                float s = (a > 0.0f) ? 1.0f : -1.0f;
                c = cc; da = s * w3 * a; db = s * w3 * b;
            }
        }
        bool act;
        if (k == 0) act = (a < 0.0f) || (a == 0.0f && b > 0.0f);
        else { float v = a * lo + b; act = (v > 0.0f) || (v == 0.0f && a > 0.0f); }
        a0 = act ? w3 * a : 0.0f;
        b0 = act ? w3 * b : 0.0f;
        for (int d = 32; d; d >>= 1) { a0 += __shfl_xor(a0, d); b0 += __shfl_xor(b0, d); }

        int rank = 0;
        for (int l = 0; l < 64; ++l) {
            float o = __shfl(c, l);
            rank += (o < c) || (o == c && l < lane);
        }
        sc_[rank] = c; sda[rank] = da; sdb[rank] = db;
    }
    __syncthreads();
    if (tid < 64) {
        float cs = sc_[lane], das = sda[lane], dbs = sdb[lane];
        for (int d = 1; d < 64; d <<= 1) {  // inclusive scan in sorted order
            float ta = __shfl_up(das, d);
            float tb = __shfl_up(dbs, d);
            if (lane >= d) { das += ta; dbs += tb; }
        }
        knots[k * ROW + lane] = cs;          // inf for invalid -> fine-search safe
        if (lane == 0) coef[k * ROW] = make_float2(a0, b0);
        coef[k * ROW + lane + 1] = make_float2(a0 + das, b0 + dbs);
    }
}

// two-level flat index for x: coarse k over bps, fine j over row k (R3-verified)
__device__ __forceinline__ int locate(const float* __restrict__ bps_s,
                                      const float* __restrict__ T2_s, float xv)
{
    int k = 0;                     // coarse: k = #{bps <= xv} in [0,64]
#pragma unroll
    for (int ofs = 32; ofs >= 1; ofs >>= 1)
        if (bps_s[k + ofs - 1] <= xv) k += ofs;
    k += (k < 64 && bps_s[k] <= xv) ? 1 : 0;
    const int kb = k * ROW;
    int j = 0;                     // fine: j = #{row-k knots <= xv} in [0,64]
#pragma unroll
    for (int ofs = 32; ofs >= 1; ofs >>= 1)
        if (T2_s[kb + j + ofs - 1] <= xv) j += ofs;
    j += (j < 64 && T2_s[kb + j] <= xv) ? 1 : 0;
    return kb + j;
}

// ---- K2: one block per segment -> vectorized two-level eval, f64 reduce,
//          broadcast write ----
__global__ __launch_bounds__(256) void k_eval_out(
    const float* __restrict__ x,
    const int* __restrict__ seg_start, const int* __restrict__ seg_end,
    const float* __restrict__ bpg, const float* __restrict__ knots2d,
    const float2* __restrict__ coef2d,
    const float* __restrict__ b3, float* __restrict__ out)
{
    __shared__ float bps_s[64];
    __shared__ __align__(16) float T2_s[N2D];
    __shared__ double wsum[4];
    __shared__ float w_s;
    const int tid = threadIdx.x;
    const int s = blockIdx.x;

    // stage breakpoints + 2D knot table (17 KB, float4, all threads)
    if (tid < 64) bps_s[tid] = bpg[tid];
    for (int i = tid; i < (N2D >> 2); i += 256)
        ((float4*)T2_s)[i] = ((const float4*)knots2d)[i];
    if (tid == 0) T2_s[N2D - 1] = knots2d[N2D - 1];

    const int start = seg_start[s];
    const int end   = seg_end[s];
    __syncthreads();
    if (start >= end) return;          // empty segment: nothing to write

    // alignment split: scalar head [start,A), float4 body [A,B), scalar tail [B,end)
    const int A = min((start + 3) & ~3, end);
    const int B = A + ((end - A) & ~3);

    double acc = 0.0;
    if (start + tid < A) {             // head (<=3 points)
        float xv = x[start + tid];
        float2 ab = coef2d[locate(bps_s, T2_s, xv)];
        acc += (double)fmaf(ab.x, xv, ab.y);
    }
    for (int i = A + (tid << 2); i < B; i += 1024) {   // vector body
        float4 x4 = *(const float4*)(x + i);
        // phase A: 4 independent search chains issue together
        int m0 = locate(bps_s, T2_s, x4.x);
        int m1 = locate(bps_s, T2_s, x4.y);
        int m2 = locate(bps_s, T2_s, x4.z);
        int m3 = locate(bps_s, T2_s, x4.w);
        // phase B: 4 coef loads in flight
        float2 c0 = coef2d[m0], c1 = coef2d[m1], c2 = coef2d[m2], c3 = coef2d[m3];
        // phase C: in-order accumulate (deterministic)
        acc += (double)fmaf(c0.x, x4.x, c0.y);
        acc += (double)fmaf(c1.x, x4.y, c1.y);
        acc += (double)fmaf(c2.x, x4.z, c2.y);
        acc += (double)fmaf(c3.x, x4.w, c3.y);
    }
    if (B + tid < end) {               // tail (<=3 points)
        float xv = x[B + tid];
        float2 ab = coef2d[locate(bps_s, T2_s, xv)];
        acc += (double)fmaf(ab.x, xv, ab.y);
    }

    // deterministic tree reduction: wave shfl + 4 partials in LDS
    for (int d = 32; d; d >>= 1) acc += __shfl_down(acc, d);
    if ((tid & 63) == 0) wsum[tid >> 6] = acc;
    __syncthreads();
    if (tid == 0) {
        double tot = wsum[0] + wsum[1] + wsum[2] + wsum[3];
        double mean = tot / (double)(end - start);
        w_s = fmaxf((float)(mean + (double)b3[0]), 0.0f);
    }
    __syncthreads();
    const float w = w_s;

    // vectorized broadcast write
    if (start + tid < A) out[start + tid] = w;
    float4 w4 = make_float4(w, w, w, w);
    for (int i = A + (tid << 2); i < B; i += 1024)
        *(float4*)(out + i) = w4;
    if (B + tid < end) out[B + tid] = w;
}

extern "C" void kernel_launch(void* const* d_in, const int* in_sizes, int n_in,
                              void* d_out, int out_size, void* d_ws, size_t ws_size,
                              hipStream_t stream)
{
    const float* x   = (const float*)d_in[0];
    const int* batch = (const int*)d_in[1];
    const float* W1 = (const float*)d_in[2];
    const float* b1 = (const float*)d_in[3];
    const float* W2 = (const float*)d_in[4];
    const float* b2 = (const float*)d_in[5];
    const float* W3 = (const float*)d_in[6];
    const float* b3 = (const float*)d_in[7];
    float* out = (float*)d_out;
    const int n = in_sizes[0];

    char* ws = (char*)d_ws;
    int*    seg_start= (int*)ws;                            //  8192  -> 8192
    int*    seg_end  = (int*)(ws + 8192);                   //  8192  -> 16384
    float*  bpg      = (float*)(ws + 16384);                //   256  -> 16640
    float*  knots2d  = (float*)(ws + 16640);                // 16912  -> 33552
    float2* coef2d   = (float2*)(ws + 33552);               // 33808  -> 67360

    const int scanBlocks = (n + 256 * SCAN_PPT - 1) / (256 * SCAN_PPT);
    k_pre_scan<<<65 + scanBlocks, 256, 0, stream>>>(
        W1, b1, W2, b2, W3, batch, bpg, knots2d, coef2d,
        seg_start, seg_end, n);
    k_eval_out<<<NSEG, 256, 0, stream>>>(x, seg_start, seg_end, bpg,
                                         knots2d, coef2d, b3, out);
}